// Round 8
// baseline (197.068 us; speedup 1.0000x reference)
//
#include <hip/hip_runtime.h>
#include <hip/hip_bf16.h>

#define DD 256
#define BB 2048
#define BM 128                   // c3 rows per block tile (j-half of one i)
#define BN 32                    // batch columns per pipeline stage
#define NTILE 512                // 256 i x 2 j-halves -> exactly 2 blocks/CU
#define NSTAGE (BB / BN)         // 64 pipeline iterations
#define NBUF 4                   // quad-buffered B tiles, prefetch depth 3

typedef __bf16 bf16x8 __attribute__((ext_vector_type(8)));
typedef float  f32x4  __attribute__((ext_vector_type(4)));

#define AS1 __attribute__((address_space(1)))
#define AS3 __attribute__((address_space(3)))

__device__ __forceinline__ unsigned short f2bf(float f) {
    unsigned int u = __float_as_uint(f);
    return (unsigned short)((u + 0x7FFFu + ((u >> 16) & 1u)) >> 16);  // RNE
}
__device__ __forceinline__ float bf2f(unsigned short s) {
    return __uint_as_float(((unsigned int)s) << 16);
}
__device__ __forceinline__ void async_cp16(const void* g, void* l) {
    __builtin_amdgcn_global_load_lds((const AS1 unsigned int*)g,
                                     (AS3 unsigned int*)l, 16, 0, 0);
}

// K1: rel = x - offsets -> bf16 (all downstream consumers) and out[b] = c0 + <c1, rel_b>
__global__ void prep_all(const float* __restrict__ x, const float* __restrict__ offsets,
                         const float* __restrict__ c0, const float* __restrict__ c1,
                         unsigned short* __restrict__ rel_bf16, float* __restrict__ out) {
    const int tid = threadIdx.x, wave = tid >> 6, lane = tid & 63;
    const float4 o4  = *(const float4*)(offsets + lane * 4);
    const float4 c14 = *(const float4*)(c1 + lane * 4);
#pragma unroll
    for (int i = 0; i < 2; ++i) {
        const int b = blockIdx.x * 8 + wave * 2 + i;
        const float4 x4 = *(const float4*)(x + (size_t)b * DD + lane * 4);
        float4 r;
        r.x = x4.x - o4.x; r.y = x4.y - o4.y; r.z = x4.z - o4.z; r.w = x4.w - o4.w;
        ushort4 rb;
        rb.x = f2bf(r.x); rb.y = f2bf(r.y); rb.z = f2bf(r.z); rb.w = f2bf(r.w);
        *(ushort4*)(rel_bf16 + (size_t)b * DD + lane * 4) = rb;
        float s = r.x * c14.x + r.y * c14.y + r.z * c14.z + r.w * c14.w;
        s += __shfl_xor(s, 1);  s += __shfl_xor(s, 2);  s += __shfl_xor(s, 4);
        s += __shfl_xor(s, 8);  s += __shfl_xor(s, 16); s += __shfl_xor(s, 32);
        if (lane == 0) out[b] = c0[0] + s;
    }
}

// K3: fused GEMM (c3 j-half tile @ rel^T) + c2 fold + weighted column reduction.
// Geometry frozen at R7 (proven: no spill, 44% occupancy). One change: counted-vmcnt
// pipeline (T4). 4 LDS buffers, prefetch 3 stages ahead, raw s_barrier + per-wave
// s_waitcnt vmcnt(4) steady state (loads for t+1,t+2 stay in flight across barriers).
// Tail peeled with vmcnt 4/4/2/0. 2 loads/thread/stage -> counts are exact.
__global__ __launch_bounds__(512, 4) void taylor3(
    const float* __restrict__ c3, const float* __restrict__ c2,
    const unsigned short* __restrict__ rel_bf16, float* __restrict__ partial)
{
    __shared__ unsigned short Bs[NBUF][BN * DD];       // 64 KB, quad-buffered
    __shared__ unsigned short relIbf[BB];              // 4 KB: rel[:, i_t] bf16
    __shared__ __align__(16) float c2row[BM];          // 512 B: c2[i_t, jbase..+128)
    __shared__ float colsum[2][8][BN];                 // 2 KB, per-wave partials, dbuf

    const int bidx  = blockIdx.x;
    const int i_t   = bidx >> 1;
    const int jbase = (bidx & 1) << 7;
    const int tid  = threadIdx.x;
    const int wave = tid >> 6;
    const int lane = tid & 63;
    const int wm = wave & 1, wk = wave >> 1;           // wm: row half, wk: k quarter
    const int lrow = lane & 15, quad = lane >> 4;

    // stage rel[:, i_t] (bf16) into LDS, one-time
#pragma unroll
    for (int k = 0; k < 4; ++k) {
        const int b = tid + k * 512;
        relIbf[b] = rel_bf16[(size_t)b * DD + i_t];
    }
    if (tid < BM) c2row[tid] = c2[i_t * DD + jbase + tid];

    __syncthreads();   // relIbf/c2row visible to all waves; prefetches issued after

    // ---- async stage: tile nb -> Bs[buf]; 2 loads/thread, swizzled granules ----
    auto stage = [&](int nb, int buf) {
        const int b0 = nb * BN;
#pragma unroll
        for (int c = 0; c < 2; ++c) {
            const int r0 = c * 16 + wave * 2;           // wave-uniform base row (0..31)
            const int row = r0 + (lane >> 5);
            const int g = (lane & 31) ^ (row & 7);      // logical granule for this phys slot
            const unsigned short* src = rel_bf16 + (size_t)(b0 + row) * DD + g * 8;
            async_cp16(src, &Bs[buf][r0 * DD]);
        }
    };

    stage(0, 0); stage(1, 1); stage(2, 2);   // depth-3 prologue (6 outstanding/thread)

    // ---- hoist A fragments: 64 rows (mt=4) x own 64-k quarter -> 32 VGPRs ----
    // (long global-load sequence; covers the prologue prefetch latency)
    bf16x8 afr[2][4];
    {
#pragma unroll
        for (int mt = 0; mt < 4; ++mt) {
            const int j = jbase + wm * 64 + mt * 16 + lrow;
            const float* p = c3 + ((size_t)i_t * DD + j) * DD + wk * 64 + quad * 8;
#pragma unroll
            for (int ks = 0; ks < 2; ++ks) {
                const float4 f0 = *(const float4*)(p + ks * 32);
                const float4 f1 = *(const float4*)(p + ks * 32 + 4);
                union { unsigned short u[8]; bf16x8 v; } cv;
                cv.u[0] = f2bf(f0.x); cv.u[1] = f2bf(f0.y);
                cv.u[2] = f2bf(f0.z); cv.u[3] = f2bf(f0.w);
                cv.u[4] = f2bf(f1.x); cv.u[5] = f2bf(f1.y);
                cv.u[6] = f2bf(f1.z); cv.u[7] = f2bf(f1.w);
                afr[ks][mt] = cv.v;
            }
        }
    }

    // ---- one pipeline stage; cur and vm are literals at every call site ----
    auto body = [&](int nb, int cur, int vm) {
        // wait own prefetch of Bs[cur] (leave vm newer loads in flight), then barrier:
        // after it, ALL waves' Bs[cur] loads are complete (each waited before barrier).
        if (vm == 4)      asm volatile("s_waitcnt vmcnt(4)" ::: "memory");
        else if (vm == 2) asm volatile("s_waitcnt vmcnt(2)" ::: "memory");
        else              asm volatile("s_waitcnt vmcnt(0)" ::: "memory");
        __builtin_amdgcn_s_barrier();

        // issue prefetch 3 ahead into buf (cur+3)&3 = (cur-1)&3, last read in stage
        // nb-1 (strictly before this barrier) -> WAR-safe.
        if (nb + 3 < NSTAGE) stage(nb + 3, (cur + 3) & 3);

        // combine previous stage's colsum (parity (nb-1)&1); plain coalesced store
        if (nb > 0 && wave == 0 && lane < BN) {
            const int pb0 = nb * BN - BN;
            float v = colsum[(nb - 1) & 1][0][lane];
#pragma unroll
            for (int w = 1; w < 8; ++w) v += colsum[(nb - 1) & 1][w][lane];
            partial[(size_t)bidx * BB + pb0 + lane] = bf2f(relIbf[pb0 + lane]) * v;
        }

        f32x4 acc[4][2];
        __builtin_amdgcn_s_setprio(1);
        // ---- K-loop: 2 steps of 16x16x32 over this wave's 64-k quarter; ks=0 peeled ----
        {
            bf16x8 bfr[2];
#pragma unroll
            for (int nt = 0; nt < 2; ++nt) {
                const int col = nt * 16 + lrow;
                const int glog = wk * 8 + quad;
                const int g = glog ^ (col & 7);
                bfr[nt] = *(const bf16x8*)(&Bs[cur][col * DD + g * 8]);
            }
            const f32x4 z4 = (f32x4){0.f, 0.f, 0.f, 0.f};
#pragma unroll
            for (int mt = 0; mt < 4; ++mt)
#pragma unroll
                for (int nt = 0; nt < 2; ++nt)
                    acc[mt][nt] = __builtin_amdgcn_mfma_f32_16x16x32_bf16(
                        afr[0][mt], bfr[nt], z4, 0, 0, 0);
        }
        {
            bf16x8 bfr[2];
#pragma unroll
            for (int nt = 0; nt < 2; ++nt) {
                const int col = nt * 16 + lrow;
                const int glog = wk * 8 + 4 + quad;
                const int g = glog ^ (col & 7);
                bfr[nt] = *(const bf16x8*)(&Bs[cur][col * DD + g * 8]);
            }
#pragma unroll
            for (int mt = 0; mt < 4; ++mt)
#pragma unroll
                for (int nt = 0; nt < 2; ++nt)
                    acc[mt][nt] = __builtin_amdgcn_mfma_f32_16x16x32_bf16(
                        afr[1][mt], bfr[nt], acc[mt][nt], 0, 0, 0);
        }
        __builtin_amdgcn_s_setprio(0);

        // ---- epilogue: s(col) = sum_rows (G + c2?) * r[b, j(row)]; indep chains ----
        float sv[2];
#pragma unroll
        for (int nt = 0; nt < 2; ++nt) {
            const int col = nt * 16 + lrow;
            float s0 = 0.f, s1 = 0.f;
#pragma unroll
            for (int mt = 0; mt < 4; ++mt) {
                const int el = wm * 64 + mt * 16 + quad * 4;    // local j (0..127)
                const int e  = jbase + el;                      // global j
                const int g  = (e >> 3) ^ (col & 7);
                const ushort4 rj = *(const ushort4*)(&Bs[cur][col * DD + g * 8 + (e & 7)]);
                f32x4 a = acc[mt][nt];
                if (wk == 0) {   // c2 folded exactly once, wave-uniform branch
                    const float4 c2r = *(const float4*)(&c2row[el]);
                    a[0] += c2r.x; a[1] += c2r.y; a[2] += c2r.z; a[3] += c2r.w;
                }
                float& sa = (mt & 1) ? s1 : s0;   // mt is compile-time constant
                sa = fmaf(a[0], bf2f(rj.x), sa);
                sa = fmaf(a[1], bf2f(rj.y), sa);
                sa = fmaf(a[2], bf2f(rj.z), sa);
                sa = fmaf(a[3], bf2f(rj.w), sa);
            }
            float s = s0 + s1;
            s += __shfl_xor(s, 16, 64);
            s += __shfl_xor(s, 32, 64);   // all lanes hold the column total
            sv[nt] = s;
        }
        // lanes 0..31 write this wave's 32 columns (parity nb&1)
        if (lane < 32)
            colsum[nb & 1][wave][lane] = (lane & 16) ? sv[1] : sv[0];
    };

    // main loop: steady-state vmcnt(4); tail peeled 60..63 with 4/4/2/0
    for (int t = 0; t < 60; t += 4) {
        body(t,     0, 4);
        body(t + 1, 1, 4);
        body(t + 2, 2, 4);
        body(t + 3, 3, 4);
    }
    body(60, 0, 4);
    body(61, 1, 4);
    body(62, 2, 2);
    body(63, 3, 0);

    __syncthreads();
    if (wave == 0 && lane < BN) {   // final combine, parity 63&1 = 1
        const int pb0 = BB - BN;
        float v = colsum[1][0][lane];
#pragma unroll
        for (int w = 1; w < 8; ++w) v += colsum[1][w][lane];
        partial[(size_t)bidx * BB + pb0 + lane] = bf2f(relIbf[pb0 + lane]) * v;
    }
}

// K4: out[b] += sum over 512 partial rows. 128 blocks x 256 threads.
__global__ void reduce_partial(const float* __restrict__ partial, float* __restrict__ out) {
    __shared__ f32x4 red[256];
    const int t = threadIdx.x;
    const int g = blockIdx.x * 4 + (t & 3);   // float4 column group (512 total)
    const int slice = t >> 2;                 // 64 row-slices of 8 rows
    f32x4 s = (f32x4){0.f, 0.f, 0.f, 0.f};
    for (int r = slice * 8; r < slice * 8 + 8; ++r)
        s += *(const f32x4*)(partial + (size_t)r * BB + g * 4);
    red[t] = s; __syncthreads();
    if (t < 128) red[t] += red[t + 128]; __syncthreads();
    if (t < 64)  red[t] += red[t + 64];  __syncthreads();
    if (t < 32)  red[t] += red[t + 32];  __syncthreads();
    if (t < 16)  red[t] += red[t + 16];  __syncthreads();
    if (t < 8)   red[t] += red[t + 8];   __syncthreads();
    if (t < 4) {
        const f32x4 v = red[t] + red[t + 4];
        float4* op = (float4*)(out + (size_t)(blockIdx.x * 4 + t) * 4);
        float4 o = *op;
        o.x += v[0]; o.y += v[1]; o.z += v[2]; o.w += v[3];
        *op = o;
    }
}

extern "C" void kernel_launch(void* const* d_in, const int* in_sizes, int n_in,
                              void* d_out, int out_size, void* d_ws, size_t ws_size,
                              hipStream_t stream) {
    const float* x       = (const float*)d_in[0];
    const float* offsets = (const float*)d_in[1];
    const float* c0      = (const float*)d_in[2];
    const float* c1      = (const float*)d_in[3];
    const float* c2      = (const float*)d_in[4];
    const float* c3      = (const float*)d_in[5];
    float* out = (float*)d_out;

    char* ws = (char*)d_ws;
    unsigned short* rel_bf16 = (unsigned short*)ws;                      // 1 MB
    float* partial = (float*)(ws + (size_t)1 * 1024 * 1024);             // 4 MB (512 x 2048)

    prep_all<<<BB / 8, 256, 0, stream>>>(x, offsets, c0, c1, rel_bf16, out);
    taylor3<<<NTILE, 512, 0, stream>>>(c3, c2, rel_bf16, partial);
    reduce_partial<<<128, 256, 0, stream>>>(partial, out);
}